// Round 1
// baseline (749.372 us; speedup 1.0000x reference)
//
#include <hip/hip_runtime.h>
#include <hip/hip_bf16.h>

// CGConv fused kernel for MI355X (gfx950).
// Reference: gates = sigmoid(concat @ W_e + b_e); msgs = softplus(concat @ W_n + b_n)
//            out = h + segment_sum(gates*msgs, dst) / max(deg(dst),1)
// concat = [h[src] (96) | h[dst] (96) | edge_attr (64)]  -> K = 256
//
// Strategy: bf16 MFMA (16x16x32) edge-tile GEMM, fused activation epilogue,
// fp32 atomic scatter into workspace accumulator, separate finalize kernel.

#define NODE_DIM 96
#define EDGE_DIM 64
#define IN_DIM   256      // K
#define TILE_E   64       // edges per block (M)
#define NT_TILES 12       // 192 output cols = 96 gates + 96 msgs, /16
#define KT_TILES 8        // 256 / 32
#define A_STRIDE 272      // 256 + 16 pad (keeps 16B alignment of rows, breaks pow2 banks)

typedef float  f32x4  __attribute__((ext_vector_type(4)));
typedef __bf16 bf16x8 __attribute__((ext_vector_type(8)));

__device__ __forceinline__ unsigned short bf16rne(float f) {
    unsigned int u = __float_as_uint(f);
    u += 0x7FFFu + ((u >> 16) & 1u);   // round-to-nearest-even (NaN not expected)
    return (unsigned short)(u >> 16);
}

// ---------------------------------------------------------------------------
// Pack W_e (256x96) and W_n (256x96) fp32 row-major into bf16 MFMA B-fragment
// order: tile (kt, nt), lane l, j=0..7 ->  W[kt*32 + (l>>4)*8 + j][ (nt%6)*16 + (l&15) ]
// nt 0..5 -> W_e, nt 6..11 -> W_n. One 16B store per thread.
// ---------------------------------------------------------------------------
__global__ void pack_w_kernel(const float* __restrict__ We,
                              const float* __restrict__ Wn,
                              unsigned short* __restrict__ bpack) {
    int t = blockIdx.x * blockDim.x + threadIdx.x;     // 0 .. 96*64-1
    if (t >= KT_TILES * NT_TILES * 64) return;
    int tile = t >> 6, lane = t & 63;
    int kt = tile / NT_TILES, nt = tile % NT_TILES;
    const float* W = (nt < 6) ? We : Wn;
    int n  = (nt % 6) * 16 + (lane & 15);
    int k0 = kt * 32 + (lane >> 4) * 8;
    union { unsigned short u[8]; uint4 v; } tmp;
#pragma unroll
    for (int j = 0; j < 8; ++j) tmp.u[j] = bf16rne(W[(k0 + j) * NODE_DIM + n]);
    *(uint4*)(bpack + (size_t)t * 8) = tmp.v;
}

// ---------------------------------------------------------------------------
// Main fused kernel: one block = 64 edges.
// ---------------------------------------------------------------------------
__global__ __launch_bounds__(256)
void cgconv_main_kernel(const float* __restrict__ h,
                        const int*   __restrict__ eidx,   // [2*E]: src then dst
                        const float* __restrict__ ea,     // [E,64]
                        const unsigned short* __restrict__ bpack,
                        const float* __restrict__ be,
                        const float* __restrict__ bn,
                        float* __restrict__ hnew,
                        float* __restrict__ cnt,
                        int E) {
    __shared__ unsigned short sA[TILE_E][A_STRIDE];
    __shared__ int s_src[TILE_E];
    __shared__ int s_dst[TILE_E];

    const int tid = threadIdx.x;
    const int e0  = blockIdx.x * TILE_E;

    if (tid < TILE_E) {
        int e = e0 + tid;
        int s = 0, d = -1;
        if (e < E) {
            s = eidx[e];
            d = eidx[E + e];
            unsafeAtomicAdd(cnt + d, 1.0f);
        }
        s_src[tid] = s;
        s_dst[tid] = d;
    }
    __syncthreads();

    // ---- stage A tile into LDS as bf16 -----------------------------------
    // cols 0..95 : h[src]
    for (int idx = tid; idx < TILE_E * 24; idx += 256) {
        int e = idx / 24, q = idx - e * 24;
        const float4 v = *(const float4*)(h + (size_t)s_src[e] * NODE_DIM + q * 4);
        union { unsigned short u[4]; uint2 w; } p;
        p.u[0] = bf16rne(v.x); p.u[1] = bf16rne(v.y);
        p.u[2] = bf16rne(v.z); p.u[3] = bf16rne(v.w);
        *(uint2*)&sA[e][q * 4] = p.w;
    }
    // cols 96..191 : h[dst]
    for (int idx = tid; idx < TILE_E * 24; idx += 256) {
        int e = idx / 24, q = idx - e * 24;
        int d = s_dst[e]; if (d < 0) d = 0;
        const float4 v = *(const float4*)(h + (size_t)d * NODE_DIM + q * 4);
        union { unsigned short u[4]; uint2 w; } p;
        p.u[0] = bf16rne(v.x); p.u[1] = bf16rne(v.y);
        p.u[2] = bf16rne(v.z); p.u[3] = bf16rne(v.w);
        *(uint2*)&sA[e][NODE_DIM + q * 4] = p.w;
    }
    // cols 192..255 : edge_attr
    for (int idx = tid; idx < TILE_E * 16; idx += 256) {
        int e = idx >> 4, q = idx & 15;
        size_t ee = (size_t)(e0 + e);
        if (e0 + e >= E) ee = (size_t)e0;   // harmless dup for tail
        const float4 v = *(const float4*)(ea + ee * EDGE_DIM + q * 4);
        union { unsigned short u[4]; uint2 w; } p;
        p.u[0] = bf16rne(v.x); p.u[1] = bf16rne(v.y);
        p.u[2] = bf16rne(v.z); p.u[3] = bf16rne(v.w);
        *(uint2*)&sA[e][2 * NODE_DIM + q * 4] = p.w;
    }
    __syncthreads();

    // ---- MFMA GEMM: wave w handles rows [16w,16w+16), all 12 col tiles ----
    const int wave = tid >> 6, lane = tid & 63;
    const int lrow = lane & 15, lquad = lane >> 4;

    f32x4 acc[NT_TILES];
#pragma unroll
    for (int nt = 0; nt < NT_TILES; ++nt) acc[nt] = (f32x4){0.f, 0.f, 0.f, 0.f};

    const unsigned short* aBase = &sA[wave * 16 + lrow][0];
#pragma unroll
    for (int kt = 0; kt < KT_TILES; ++kt) {
        bf16x8 afrag = *(const bf16x8*)(aBase + kt * 32 + lquad * 8);
#pragma unroll
        for (int nt = 0; nt < NT_TILES; ++nt) {
            bf16x8 bfrag = *(const bf16x8*)(bpack +
                             (size_t)((kt * NT_TILES + nt) * 64 + lane) * 8);
            acc[nt] = __builtin_amdgcn_mfma_f32_16x16x32_bf16(afrag, bfrag, acc[nt], 0, 0, 0);
        }
    }

    // ---- epilogue: sigmoid(gate) * softplus(msg), atomic scatter to dst ---
    // C layout: col = lane&15, row = (lane>>4)*4 + reg
#pragma unroll
    for (int nt = 0; nt < 6; ++nt) {
        const int col = nt * 16 + lrow;
        const float bev = be[col];
        const float bnv = bn[col];
#pragma unroll
        for (int r = 0; r < 4; ++r) {
            const int row = wave * 16 + lquad * 4 + r;
            const int d = s_dst[row];
            if (d < 0) continue;
            float g = acc[nt][r] + bev;
            float m = acc[nt + 6][r] + bnv;
            float gate = 1.0f / (1.0f + __expf(-g));
            float sp   = fmaxf(m, 0.0f) + __logf(1.0f + __expf(-fabsf(m)));
            unsafeAtomicAdd(hnew + (size_t)d * NODE_DIM + col, gate * sp);
        }
    }
}

// ---------------------------------------------------------------------------
// finalize: out = h + hnew / max(cnt,1)
// ---------------------------------------------------------------------------
__global__ void finalize_kernel(const float* __restrict__ h,
                                const float* __restrict__ hnew,
                                const float* __restrict__ cnt,
                                float* __restrict__ out,
                                int total4) {      // N * 24 float4 groups
    int i = blockIdx.x * blockDim.x + threadIdx.x;
    if (i >= total4) return;
    int n = i / 24;
    float c = fmaxf(cnt[n], 1.0f);
    float inv = 1.0f / c;
    float4 hv = ((const float4*)h)[i];
    float4 av = ((const float4*)hnew)[i];
    float4 o;
    o.x = hv.x + av.x * inv;
    o.y = hv.y + av.y * inv;
    o.z = hv.z + av.z * inv;
    o.w = hv.w + av.w * inv;
    ((float4*)out)[i] = o;
}

// ---------------------------------------------------------------------------
extern "C" void kernel_launch(void* const* d_in, const int* in_sizes, int n_in,
                              void* d_out, int out_size, void* d_ws, size_t ws_size,
                              hipStream_t stream) {
    const float* h   = (const float*)d_in[0];
    const int*   ei  = (const int*)  d_in[1];
    const float* ea  = (const float*)d_in[2];
    const float* We  = (const float*)d_in[3];
    const float* be  = (const float*)d_in[4];
    const float* Wn  = (const float*)d_in[5];
    const float* bn  = (const float*)d_in[6];

    const int N = in_sizes[0] / NODE_DIM;     // 50000
    const int E = in_sizes[2] / EDGE_DIM;     // 800000

    // workspace layout
    char* ws = (char*)d_ws;
    const size_t BPACK_BYTES = (size_t)KT_TILES * NT_TILES * 64 * 8 * 2;  // 96 KB
    const size_t CNT_OFF  = BPACK_BYTES;                                   // N*4
    const size_t HNEW_OFF = CNT_OFF + (((size_t)N * 4 + 511) / 512) * 512;
    const size_t HNEW_BYTES = (size_t)N * NODE_DIM * 4;

    unsigned short* bpack = (unsigned short*)ws;
    float* cnt  = (float*)(ws + CNT_OFF);
    float* hnew = (float*)(ws + HNEW_OFF);

    // zero accumulators (ws is poisoned 0xAA before every launch)
    hipMemsetAsync(ws + CNT_OFF, 0, HNEW_OFF - CNT_OFF + HNEW_BYTES, stream);

    pack_w_kernel<<<(KT_TILES * NT_TILES * 64 + 255) / 256, 256, 0, stream>>>(We, Wn, bpack);

    const int nblk = (E + TILE_E - 1) / TILE_E;   // 12500
    cgconv_main_kernel<<<nblk, 256, 0, stream>>>(h, ei, ea, bpack, be, bn, hnew, cnt, E);

    const int total4 = N * (NODE_DIM / 4);        // 1.2M float4 groups
    finalize_kernel<<<(total4 + 255) / 256, 256, 0, stream>>>(h, hnew, cnt, (float*)d_out, total4);
}

// Round 2
// 738.570 us; speedup vs baseline: 1.0146x; 1.0146x over previous
//
#include <hip/hip_runtime.h>
#include <hip/hip_bf16.h>

// CGConv fused kernel for MI355X (gfx950) — round 2: register-direct A.
// gates = sigmoid(concat @ W_e + b_e); msgs = softplus(concat @ W_n + b_n)
// out = h + segment_sum(gates*msgs, dst) / max(deg(dst),1)
// concat = [h[src] (96) | h[dst] (96) | edge_attr (64)] -> K = 256
//
// R2 change: no LDS, no __syncthreads. Each lane loads its own A-fragment
// (8 consecutive fp32 = 32B, 16B-aligned) directly from global and converts
// to bf16 in-register. MFMA A-layout: row m = lane&15, k = quad*8+j, so a
// wave's loads cover 16 edge-rows x 128B contiguous chunks — same HBM traffic
// as the LDS version, zero staging serialization. dst indices shared via shfl.

#define NODE_DIM 96
#define EDGE_DIM 64
#define IN_DIM   256      // K
#define TILE_E   64       // edges per block (4 waves x 16 rows)
#define NT_TILES 12       // 192 output cols = 96 gates + 96 msgs
#define KT_TILES 8        // 256 / 32

typedef float  f32x4  __attribute__((ext_vector_type(4)));
typedef __bf16 bf16x8 __attribute__((ext_vector_type(8)));

__device__ __forceinline__ unsigned short bf16rne(float f) {
    unsigned int u = __float_as_uint(f);
    u += 0x7FFFu + ((u >> 16) & 1u);   // round-to-nearest-even
    return (unsigned short)(u >> 16);
}

// ---------------------------------------------------------------------------
// Pack W_e (256x96) and W_n (256x96) fp32 row-major into bf16 MFMA B-fragment
// order: tile (kt, nt), lane l, j=0..7 -> W[kt*32 + (l>>4)*8 + j][(nt%6)*16 + (l&15)]
// nt 0..5 -> W_e, nt 6..11 -> W_n.
// ---------------------------------------------------------------------------
__global__ void pack_w_kernel(const float* __restrict__ We,
                              const float* __restrict__ Wn,
                              unsigned short* __restrict__ bpack) {
    int t = blockIdx.x * blockDim.x + threadIdx.x;     // 0 .. 96*64-1
    if (t >= KT_TILES * NT_TILES * 64) return;
    int tile = t >> 6, lane = t & 63;
    int kt = tile / NT_TILES, nt = tile % NT_TILES;
    const float* W = (nt < 6) ? We : Wn;
    int n  = (nt % 6) * 16 + (lane & 15);
    int k0 = kt * 32 + (lane >> 4) * 8;
    union { unsigned short u[8]; uint4 v; } tmp;
#pragma unroll
    for (int j = 0; j < 8; ++j) tmp.u[j] = bf16rne(W[(k0 + j) * NODE_DIM + n]);
    *(uint4*)(bpack + (size_t)t * 8) = tmp.v;
}

// ---------------------------------------------------------------------------
// Main fused kernel: one block = 64 edges, 4 waves, wave w owns rows [16w,16w+16).
// No LDS, no barriers.
// ---------------------------------------------------------------------------
__global__ __launch_bounds__(256, 4)
void cgconv_main_kernel(const float* __restrict__ h,
                        const int*   __restrict__ eidx,   // [2*E]: src then dst
                        const float* __restrict__ ea,     // [E,64]
                        const unsigned short* __restrict__ bpack,
                        const float* __restrict__ be,
                        const float* __restrict__ bn,
                        float* __restrict__ hnew,
                        float* __restrict__ cnt,
                        int E) {
    const int tid  = threadIdx.x;
    const int wave = tid >> 6, lane = tid & 63;
    const int m    = lane & 15;          // A row within the wave tile
    const int quad = lane >> 4;          // k-chunk selector

    const int e  = blockIdx.x * TILE_E + wave * 16 + m;
    const int eg = (e < E) ? e : (E - 1);     // clamped for loads
    const int src = eidx[eg];
    const int dst = eidx[E + eg];

    if (quad == 0 && e < E) unsafeAtomicAdd(cnt + dst, 1.0f);

    f32x4 acc[NT_TILES];
#pragma unroll
    for (int nt = 0; nt < NT_TILES; ++nt) acc[nt] = (f32x4){0.f, 0.f, 0.f, 0.f};

    const float* hsrc = h + (size_t)src * NODE_DIM;
    const float* hdst = h + (size_t)dst * NODE_DIM;
    const float* earo = ea + (size_t)eg * EDGE_DIM;

#pragma unroll
    for (int kt = 0; kt < KT_TILES; ++kt) {
        const int ko = kt * 32 + quad * 8;           // k offset in concat
        const float* p;
        if (kt < 3)      p = hsrc + ko;              // k in [0,96)
        else if (kt < 6) p = hdst + (ko - NODE_DIM); // k in [96,192)
        else             p = earo + (ko - 2 * NODE_DIM); // k in [192,256)
        const float4 v0 = *(const float4*)p;
        const float4 v1 = *(const float4*)(p + 4);
        union { unsigned short u[8]; bf16x8 b; } A;
        A.u[0] = bf16rne(v0.x); A.u[1] = bf16rne(v0.y);
        A.u[2] = bf16rne(v0.z); A.u[3] = bf16rne(v0.w);
        A.u[4] = bf16rne(v1.x); A.u[5] = bf16rne(v1.y);
        A.u[6] = bf16rne(v1.z); A.u[7] = bf16rne(v1.w);
#pragma unroll
        for (int nt = 0; nt < NT_TILES; ++nt) {
            bf16x8 bfrag = *(const bf16x8*)(bpack +
                             (size_t)((kt * NT_TILES + nt) * 64 + lane) * 8);
            acc[nt] = __builtin_amdgcn_mfma_f32_16x16x32_bf16(A.b, bfrag, acc[nt], 0, 0, 0);
        }
    }

    // ---- epilogue: sigmoid(gate) * softplus(msg), atomic scatter to dst ---
    // C layout: col = nt*16 + (lane&15), row (within wave tile) = quad*4 + r
    int drow[4], erow[4];
#pragma unroll
    for (int r = 0; r < 4; ++r) {
        drow[r] = __shfl(dst, quad * 4 + r, 64);   // lane rr (quad 0) holds row rr's dst
        erow[r] = blockIdx.x * TILE_E + wave * 16 + quad * 4 + r;
    }
#pragma unroll
    for (int nt = 0; nt < 6; ++nt) {
        const int col = nt * 16 + m;
        const float bev = be[col];
        const float bnv = bn[col];
#pragma unroll
        for (int r = 0; r < 4; ++r) {
            if (erow[r] >= E) continue;
            float g  = acc[nt][r] + bev;
            float mm = acc[nt + 6][r] + bnv;
            float gate = 1.0f / (1.0f + __expf(-g));
            float sp   = fmaxf(mm, 0.0f) + __logf(1.0f + __expf(-fabsf(mm)));
            unsafeAtomicAdd(hnew + (size_t)drow[r] * NODE_DIM + col, gate * sp);
        }
    }
}

// ---------------------------------------------------------------------------
// finalize: out = h + hnew / max(cnt,1)
// ---------------------------------------------------------------------------
__global__ void finalize_kernel(const float* __restrict__ h,
                                const float* __restrict__ hnew,
                                const float* __restrict__ cnt,
                                float* __restrict__ out,
                                int total4) {      // N * 24 float4 groups
    int i = blockIdx.x * blockDim.x + threadIdx.x;
    if (i >= total4) return;
    int n = i / 24;
    float c = fmaxf(cnt[n], 1.0f);
    float inv = 1.0f / c;
    float4 hv = ((const float4*)h)[i];
    float4 av = ((const float4*)hnew)[i];
    float4 o;
    o.x = hv.x + av.x * inv;
    o.y = hv.y + av.y * inv;
    o.z = hv.z + av.z * inv;
    o.w = hv.w + av.w * inv;
    ((float4*)out)[i] = o;
}

// ---------------------------------------------------------------------------
extern "C" void kernel_launch(void* const* d_in, const int* in_sizes, int n_in,
                              void* d_out, int out_size, void* d_ws, size_t ws_size,
                              hipStream_t stream) {
    const float* h   = (const float*)d_in[0];
    const int*   ei  = (const int*)  d_in[1];
    const float* ea  = (const float*)d_in[2];
    const float* We  = (const float*)d_in[3];
    const float* be  = (const float*)d_in[4];
    const float* Wn  = (const float*)d_in[5];
    const float* bn  = (const float*)d_in[6];

    const int N = in_sizes[0] / NODE_DIM;     // 50000
    const int E = in_sizes[2] / EDGE_DIM;     // 800000

    // workspace layout
    char* ws = (char*)d_ws;
    const size_t BPACK_BYTES = (size_t)KT_TILES * NT_TILES * 64 * 8 * 2;  // 96 KB
    const size_t CNT_OFF  = BPACK_BYTES;                                   // N*4
    const size_t HNEW_OFF = CNT_OFF + (((size_t)N * 4 + 511) / 512) * 512;
    const size_t HNEW_BYTES = (size_t)N * NODE_DIM * 4;

    unsigned short* bpack = (unsigned short*)ws;
    float* cnt  = (float*)(ws + CNT_OFF);
    float* hnew = (float*)(ws + HNEW_OFF);

    // zero accumulators (ws is poisoned 0xAA before every launch)
    hipMemsetAsync(ws + CNT_OFF, 0, HNEW_OFF - CNT_OFF + HNEW_BYTES, stream);

    pack_w_kernel<<<(KT_TILES * NT_TILES * 64 + 255) / 256, 256, 0, stream>>>(We, Wn, bpack);

    const int nblk = (E + TILE_E - 1) / TILE_E;   // 12500
    cgconv_main_kernel<<<nblk, 256, 0, stream>>>(h, ei, ea, bpack, be, bn, hnew, cnt, E);

    const int total4 = N * (NODE_DIM / 4);        // 1.2M float4 groups
    finalize_kernel<<<(total4 + 255) / 256, 256, 0, stream>>>(h, hnew, cnt, (float*)d_out, total4);
}